// Round 2
// baseline (96.121 us; speedup 1.0000x reference)
//
#include <hip/hip_runtime.h>

// features (B=16, C=256, H=64, W=64) fp32 -> per-pixel channel stats -> 3->16->1 MLP.
// Memory-bound: 64 MiB read, 256 KB write. Floor ~10.7 us at 6.3 TB/s.
//
// R2 change vs R1: 512-thread blocks (8 waves) x 1024 blocks = 32 waves/CU
// (max occupancy; R1 had 16). 32 channel-groups x 8 channels each, and the
// channel loop is batched 4-at-a-time so live load data stays <= ~16 VGPRs,
// letting __launch_bounds__(512,8) hold VGPR<=64 without spills.

#define C_DIM 256
#define HW4   1024   // H*W/4 = channel-plane stride in float4

__global__ __launch_bounds__(512, 8) void fis_importance_kernel(
    const float* __restrict__ features,
    const float* __restrict__ W1,   // (3,16) row-major: W1[i*16+o]
    const float* __restrict__ b1,   // (16,)
    const float* __restrict__ W2,   // (16,)
    const float* __restrict__ b2,   // (1,)
    float* __restrict__ out)        // (B,H,W) flat
{
    const int row = blockIdx.x;          // 0..B*H-1  (= b*64 + h)
    const int tid = threadIdx.x;         // 0..511
    const int w4  = tid & 15;            // float4 index along W (16 = full row)
    const int cg  = tid >> 4;            // channel group 0..31 (8 channels each)

    const int b = row >> 6;
    const int h = row & 63;

    // base float4 pointer for (b, c = cg*8, h, w = w4*4)
    const float4* fptr = reinterpret_cast<const float4*>(features)
        + ((size_t)(b * C_DIM + cg * 8) * 64 + h) * 16 + w4;

    float4 s = make_float4(0.f, 0.f, 0.f, 0.f);   // sum
    float4 q = make_float4(0.f, 0.f, 0.f, 0.f);   // sum of squares

    // two batches of 4 loads: keeps ~16 VGPRs of load data live
#pragma unroll
    for (int batch = 0; batch < 2; ++batch) {
        float4 v0 = fptr[(size_t)(batch * 4 + 0) * HW4];
        float4 v1 = fptr[(size_t)(batch * 4 + 1) * HW4];
        float4 v2 = fptr[(size_t)(batch * 4 + 2) * HW4];
        float4 v3 = fptr[(size_t)(batch * 4 + 3) * HW4];
        s.x += v0.x + v1.x + v2.x + v3.x;
        s.y += v0.y + v1.y + v2.y + v3.y;
        s.z += v0.z + v1.z + v2.z + v3.z;
        s.w += v0.w + v1.w + v2.w + v3.w;
        q.x += v0.x*v0.x + v1.x*v1.x + v2.x*v2.x + v3.x*v3.x;
        q.y += v0.y*v0.y + v1.y*v1.y + v2.y*v2.y + v3.y*v3.y;
        q.z += v0.z*v0.z + v1.z*v1.z + v2.z*v2.z + v3.z*v3.z;
        q.w += v0.w*v0.w + v1.w*v1.w + v2.w*v2.w + v3.w*v3.w;
    }

    __shared__ float4 s_sum[32][16];  // [cg][w4]  8 KB
    __shared__ float4 s_sq [32][16];  //           8 KB
    s_sum[cg][w4] = s;
    s_sq [cg][w4] = q;
    __syncthreads();

    if (tid < 64) {
        const int w   = tid;          // pixel within row
        const int ww4 = w >> 2;
        const int j   = w & 3;

        float sum = 0.f, sq = 0.f;
#pragma unroll
        for (int g = 0; g < 32; ++g) {
            // fixed g: threads 0..63 read consecutive floats -> conflict-free
            sum += reinterpret_cast<const float*>(&s_sum[g][ww4])[j];
            sq  += reinterpret_cast<const float*>(&s_sq [g][ww4])[j];
        }

        const float inv_c  = 1.0f / 256.0f;
        const float inv_c1 = 1.0f / 255.0f;

        float mag = sqrtf(sq * inv_c);                       // ||f||/sqrt(C)
        float var = (sq - sum * sum * inv_c) * inv_c1;       // unbiased
        var = fmaxf(var, 0.f);
        float stdv = sqrtf(var);

        mag = fminf(fmaxf(mag, 0.f), 1.f);
        float varc = fminf(var,  1.f);
        float grad = fminf(stdv, 1.f);

        // MLP: hk = relu(x @ W1 + b1); o = sigmoid(h @ W2 + b2)
        float o = b2[0];
#pragma unroll
        for (int k = 0; k < 16; ++k) {
            float hk = b1[k] + mag * W1[k] + varc * W1[16 + k] + grad * W1[32 + k];
            hk = fmaxf(hk, 0.f);
            o += hk * W2[k];
        }
        out[row * 64 + w] = 1.f / (1.f + __expf(-o));
    }
}

extern "C" void kernel_launch(void* const* d_in, const int* in_sizes, int n_in,
                              void* d_out, int out_size, void* d_ws, size_t ws_size,
                              hipStream_t stream) {
    const float* features = (const float*)d_in[0];
    const float* W1 = (const float*)d_in[1];
    const float* b1 = (const float*)d_in[2];
    const float* W2 = (const float*)d_in[3];
    const float* b2 = (const float*)d_in[4];
    float* out = (float*)d_out;

    // grid = B*H = 16*64 = 1024 row-blocks, 512 threads each -> 32 waves/CU
    fis_importance_kernel<<<1024, 512, 0, stream>>>(features, W1, b1, W2, b2, out);
}